// Round 1
// baseline (503.950 us; speedup 1.0000x reference)
//
#include <hip/hip_runtime.h>

#define BLOCK 256   // 4 waves per block
#define WPW   32    // rows per wave

__device__ __forceinline__ float rfl(float x) {
  // force wave-uniform value into an SGPR
  return __uint_as_float(__builtin_amdgcn_readfirstlane(__float_as_uint(x)));
}

__global__ __launch_bounds__(BLOCK, 3) void qsco_kernel(
    const float* __restrict__ E,
    const float* __restrict__ ln_gamma,
    const float* __restrict__ ln_beta,
    const float* __restrict__ Wpre,   // [8,512]
    const float* __restrict__ bpre,   // [8]
    const float* __restrict__ theta,  // [8]
    const float* __restrict__ Wpost,  // [1,8]
    const float* __restrict__ bpost,  // [1]
    float* __restrict__ out,
    int nrows)
{
  const int lane = threadIdx.x & 63;
  const int wave = blockIdx.x * (BLOCK / 64) + (threadIdx.x >> 6);
  const int row0 = wave * WPW;
  if (row0 >= nrows) return;
  const int rowEnd = min(row0 + WPW, nrows);

  // lane's k-slice: kA = 4*lane .. +3  (first half), kB = 256+4*lane .. +3
  const int kA = lane << 2;
  const int kB = 256 + (lane << 2);

  const float4 gamA = *(const float4*)(ln_gamma + kA);
  const float4 gamB = *(const float4*)(ln_gamma + kB);
  const float4 betA = *(const float4*)(ln_beta + kA);
  const float4 betB = *(const float4*)(ln_beta + kB);

  // per-wave constants: g = gamma .* Wpre rows (per-lane slice, registers),
  // G_j = sum(g_j), K_j = beta . W_j + bpre_j (uniform -> SGPR)
  float4 gv[8][2];
  float G[8], K[8];
#pragma unroll
  for (int j = 0; j < 8; ++j) {
    const float4 wA = *(const float4*)(Wpre + j * 512 + kA);
    const float4 wB = *(const float4*)(Wpre + j * 512 + kB);
    float4 ga, gb;
    ga.x = wA.x * gamA.x; ga.y = wA.y * gamA.y; ga.z = wA.z * gamA.z; ga.w = wA.w * gamA.w;
    gb.x = wB.x * gamB.x; gb.y = wB.y * gamB.y; gb.z = wB.z * gamB.z; gb.w = wB.w * gamB.w;
    gv[j][0] = ga; gv[j][1] = gb;
    float gs = (ga.x + ga.y + ga.z + ga.w) + (gb.x + gb.y + gb.z + gb.w);
    float ks = wA.x * betA.x + wA.y * betA.y + wA.z * betA.z + wA.w * betA.w
             + wB.x * betB.x + wB.y * betB.y + wB.z * betB.z + wB.w * betB.w;
#pragma unroll
    for (int m = 1; m < 64; m <<= 1) {
      gs += __shfl_xor(gs, m, 64);
      ks += __shfl_xor(ks, m, 64);
    }
    G[j] = rfl(gs);
    K[j] = rfl(ks + bpre[j]);
  }

  // theta trig (wave-invariant; same for both depth layers)
  float cT[8], sT[8];
#pragma unroll
  for (int q = 0; q < 8; ++q) {
    const float h = 0.5f * theta[q];
    cT[q] = rfl(__cosf(h));
    sT[q] = rfl(__sinf(h));
  }
  // per-lane signed sin for cross-lane RY: bit==1 -> +s, bit==0 -> -s
  float ss[6];
#pragma unroll
  for (int q = 2; q < 8; ++q)
    ss[q - 2] = ((lane >> (q - 2)) & 1) ? sT[q] : -sT[q];

  // measurement weights: D[s] = sum_i alpha_i * (1 - 2*bit_i(s))
  float al[8];
#pragma unroll
  for (int q = 0; q < 8; ++q) al[q] = rfl(Wpost[q]);
  float base = 0.f;
#pragma unroll
  for (int q = 2; q < 8; ++q)
    base += ((lane >> (q - 2)) & 1) ? -al[q] : al[q];
  const float D0 = base + al[0] + al[1];
  const float D1 = base - al[0] + al[1];
  const float D2 = base + al[0] - al[1];
  const float D3 = base - al[0] - al[1];
  const float bp = rfl(bpost[0]);

  // preload first row
  const float* Ep = E + (size_t)row0 * 512;
  float4 eA = *(const float4*)(Ep + kA);
  float4 eB = *(const float4*)(Ep + kB);

  for (int r = row0; r < rowEnd; ++r) {
    // prefetch next row
    float4 nA = eA, nB = eB;
    if (r + 1 < rowEnd) {
      const float* En = E + (size_t)(r + 1) * 512;
      nA = *(const float4*)(En + kA);
      nB = *(const float4*)(En + kB);
    }

    // 10 partial reductions: sum, sumsq, 8 dots
    float f[10];
    f[0] = (eA.x + eA.y + eA.z + eA.w) + (eB.x + eB.y + eB.z + eB.w);
    f[1] = eA.x * eA.x + eA.y * eA.y + eA.z * eA.z + eA.w * eA.w
         + eB.x * eB.x + eB.y * eB.y + eB.z * eB.z + eB.w * eB.w;
#pragma unroll
    for (int j = 0; j < 8; ++j) {
      const float4 ga = gv[j][0], gb = gv[j][1];
      f[2 + j] = eA.x * ga.x + eA.y * ga.y + eA.z * ga.z + eA.w * ga.w
               + eB.x * gb.x + eB.y * gb.y + eB.z * gb.z + eB.w * gb.w;
    }
#pragma unroll
    for (int m = 1; m < 64; m <<= 1) {
#pragma unroll
      for (int i = 0; i < 10; ++i) f[i] += __shfl_xor(f[i], m, 64);
    }

    const float mu = f[0] * (1.0f / 512.0f);
    const float var = f[1] * (1.0f / 512.0f) - mu * mu;
    const float rstd = rsqrtf(var + 1e-5f);

    float ca[8], sa[8];
#pragma unroll
    for (int j = 0; j < 8; ++j) {
      const float ang = rstd * (f[2 + j] - mu * G[j]) + K[j];
      const float h = 0.5f * ang;
      ca[j] = __cosf(h);
      sa[j] = __sinf(h);
    }

    // initial product state: qubit0 -> reg bit0, qubit1 -> reg bit1,
    // qubit q in 2..7 -> lane bit (q-2)
    float p = ((lane & 1)  ? sa[2] : ca[2]);
    p      *= ((lane & 2)  ? sa[3] : ca[3]);
    p      *= ((lane & 4)  ? sa[4] : ca[4]);
    p      *= ((lane & 8)  ? sa[5] : ca[5]);
    p      *= ((lane & 16) ? sa[6] : ca[6]);
    p      *= ((lane & 32) ? sa[7] : ca[7]);
    const float pc = p * ca[1], ps = p * sa[1];
    float a0 = pc * ca[0], a1 = pc * sa[0], a2 = ps * ca[0], a3 = ps * sa[0];

#pragma unroll
    for (int d = 0; d < 2; ++d) {
      // CNOT(0,1): j=1 <-> j=3
      { const float t = a1; a1 = a3; a3 = t; }
      // CNOT(1,2): j-bit1 set -> flip lane bit0 (unconditional for a2,a3)
      a2 = __shfl_xor(a2, 1, 64);
      a3 = __shfl_xor(a3, 1, 64);
      // CNOT(q,q+1), q=2..6: control lane bit q-2, target lane bit q-1
#pragma unroll
      for (int q = 2; q < 7; ++q) {
        const int cm = 1 << (q - 2);
        const int tm = 1 << (q - 1);
        const float v0 = __shfl_xor(a0, tm, 64);
        const float v1 = __shfl_xor(a1, tm, 64);
        const float v2 = __shfl_xor(a2, tm, 64);
        const float v3 = __shfl_xor(a3, tm, 64);
        const bool c = (lane & cm) != 0;
        a0 = c ? v0 : a0; a1 = c ? v1 : a1; a2 = c ? v2 : a2; a3 = c ? v3 : a3;
      }
      // CNOT(7,0): lanes with bit5 set swap (a0,a1) and (a2,a3)
      { const bool c = (lane & 32) != 0;
        const float t0 = c ? a1 : a0, t1 = c ? a0 : a1;
        const float t2 = c ? a3 : a2, t3 = c ? a2 : a3;
        a0 = t0; a1 = t1; a2 = t2; a3 = t3; }
      // RY qubit0: pairs (a0,a1),(a2,a3)
      { float t = a0; a0 = cT[0] * t - sT[0] * a1; a1 = sT[0] * t + cT[0] * a1;
        t = a2;       a2 = cT[0] * t - sT[0] * a3; a3 = sT[0] * t + cT[0] * a3; }
      // RY qubit1: pairs (a0,a2),(a1,a3)
      { float t = a0; a0 = cT[1] * t - sT[1] * a2; a2 = sT[1] * t + cT[1] * a2;
        t = a1;       a1 = cT[1] * t - sT[1] * a3; a3 = sT[1] * t + cT[1] * a3; }
      // RY qubits 2..7: butterfly on lane bit (q-2)
#pragma unroll
      for (int q = 2; q < 8; ++q) {
        const int m = 1 << (q - 2);
        const float p0 = __shfl_xor(a0, m, 64);
        const float p1 = __shfl_xor(a1, m, 64);
        const float p2 = __shfl_xor(a2, m, 64);
        const float p3 = __shfl_xor(a3, m, 64);
        a0 = cT[q] * a0 + ss[q - 2] * p0;
        a1 = cT[q] * a1 + ss[q - 2] * p1;
        a2 = cT[q] * a2 + ss[q - 2] * p2;
        a3 = cT[q] * a3 + ss[q - 2] * p3;
      }
    }

    // logit = sum_s |a_s|^2 * D_s + b_post
    float v = (a0 * a0) * D0 + (a1 * a1) * D1 + (a2 * a2) * D2 + (a3 * a3) * D3;
#pragma unroll
    for (int m = 1; m < 64; m <<= 1) v += __shfl_xor(v, m, 64);
    if (lane == 0) out[r] = v + bp;

    eA = nA; eB = nB;
  }
}

extern "C" void kernel_launch(void* const* d_in, const int* in_sizes, int n_in,
                              void* d_out, int out_size, void* d_ws, size_t ws_size,
                              hipStream_t stream) {
  const float* E        = (const float*)d_in[0];
  const float* ln_gamma = (const float*)d_in[1];
  const float* ln_beta  = (const float*)d_in[2];
  const float* Wpre     = (const float*)d_in[3];
  const float* bpre     = (const float*)d_in[4];
  const float* theta    = (const float*)d_in[5];
  const float* Wpost    = (const float*)d_in[6];
  const float* bpost    = (const float*)d_in[7];
  float* out = (float*)d_out;

  const int nrows = in_sizes[0] / 512;
  const int rows_per_block = (BLOCK / 64) * WPW;
  const int grid = (nrows + rows_per_block - 1) / rows_per_block;
  qsco_kernel<<<grid, BLOCK, 0, stream>>>(E, ln_gamma, ln_beta, Wpre, bpre,
                                          theta, Wpost, bpost, out, nrows);
}

// Round 2
// 396.833 us; speedup vs baseline: 1.2699x; 1.2699x over previous
//
#include <hip/hip_runtime.h>

#define BLOCK 256   // 4 waves per block
#define WPW   16    // rows per wave

__device__ __forceinline__ float rfl(float x) {
  // force wave-uniform value into an SGPR
  return __uint_as_float(__builtin_amdgcn_readfirstlane(__float_as_uint(x)));
}

// ---- DPP cross-lane xor helpers (VALU pipe, no DS traffic) ----
// All patterns chosen to be involutions => immune to shl/shr direction
// conventions. row_mask=0xf bank_mask=0xf bound_ctrl=1; all sources valid.
template<int CTRL>
__device__ __forceinline__ float dppmov(float x) {
  return __int_as_float(__builtin_amdgcn_update_dpp(
      0, __float_as_int(x), CTRL, 0xf, 0xf, true));
}
__device__ __forceinline__ float dx1(float x) { return dppmov<0xB1>(x); }  // quad_perm [1,0,3,2]
__device__ __forceinline__ float dx2(float x) { return dppmov<0x4E>(x); }  // quad_perm [2,3,0,1]
__device__ __forceinline__ float dx4(float x) {
  // xor4 = xor7 (row_half_mirror) then xor3 (quad_perm [3,2,1,0])
  return dppmov<0x1B>(dppmov<0x141>(x));
}
__device__ __forceinline__ float dx8(float x) { return dppmov<0x128>(x); } // row_ror:8 == xor8
__device__ __forceinline__ float sx16(float x) { return __shfl_xor(x, 16, 64); }
__device__ __forceinline__ float sx32(float x) { return __shfl_xor(x, 32, 64); }

template<int M>
__device__ __forceinline__ float lxor(float x) {
  if constexpr (M == 1)  return dx1(x);
  else if constexpr (M == 2)  return dx2(x);
  else if constexpr (M == 4)  return dx4(x);
  else if constexpr (M == 8)  return dx8(x);
  else if constexpr (M == 16) return sx16(x);
  else                        return sx32(x);
}

__device__ __forceinline__ float wave_allsum(float x) {
  x += dx1(x); x += dx2(x); x += dx4(x); x += dx8(x);
  x += sx16(x); x += sx32(x);
  return x;
}

__global__ __launch_bounds__(BLOCK, 4) void qsco_kernel(
    const float* __restrict__ E,
    const float* __restrict__ ln_gamma,
    const float* __restrict__ ln_beta,
    const float* __restrict__ Wpre,   // [8,512]
    const float* __restrict__ bpre,   // [8]
    const float* __restrict__ theta,  // [8]
    const float* __restrict__ Wpost,  // [1,8]
    const float* __restrict__ bpost,  // [1]
    float* __restrict__ out,
    int nrows)
{
  const int lane = threadIdx.x & 63;
  const int wave = blockIdx.x * (BLOCK / 64) + (threadIdx.x >> 6);
  const int row0 = wave * WPW;
  if (row0 >= nrows) return;
  const int rowEnd = min(row0 + WPW, nrows);

  // lane's k-slice: kA = 4*lane .. +3 (first half), kB = 256+4*lane .. +3
  const int kA = lane << 2;
  const int kB = 256 + (lane << 2);

  const float4 gamA = *(const float4*)(ln_gamma + kA);
  const float4 gamB = *(const float4*)(ln_gamma + kB);
  const float4 betA = *(const float4*)(ln_beta + kA);
  const float4 betB = *(const float4*)(ln_beta + kB);

  // per-wave constants: g = gamma .* Wpre rows (per-lane slice, registers),
  // G_j = sum(g_j), K_j = beta . W_j + bpre_j (uniform -> SGPR)
  float4 gv[8][2];
  float G[8], K[8];
#pragma unroll
  for (int j = 0; j < 8; ++j) {
    const float4 wA = *(const float4*)(Wpre + j * 512 + kA);
    const float4 wB = *(const float4*)(Wpre + j * 512 + kB);
    float4 ga, gb;
    ga.x = wA.x * gamA.x; ga.y = wA.y * gamA.y; ga.z = wA.z * gamA.z; ga.w = wA.w * gamA.w;
    gb.x = wB.x * gamB.x; gb.y = wB.y * gamB.y; gb.z = wB.z * gamB.z; gb.w = wB.w * gamB.w;
    gv[j][0] = ga; gv[j][1] = gb;
    float gs = (ga.x + ga.y + ga.z + ga.w) + (gb.x + gb.y + gb.z + gb.w);
    float ks = wA.x * betA.x + wA.y * betA.y + wA.z * betA.z + wA.w * betA.w
             + wB.x * betB.x + wB.y * betB.y + wB.z * betB.z + wB.w * betB.w;
    G[j] = rfl(wave_allsum(gs));
    K[j] = rfl(wave_allsum(ks) + bpre[j]);
  }

  // theta trig (wave-invariant; same for both depth layers)
  float cT[8], sT[8];
#pragma unroll
  for (int q = 0; q < 8; ++q) {
    const float h = 0.5f * theta[q];
    cT[q] = rfl(__cosf(h));
    sT[q] = rfl(__sinf(h));
  }
  // per-lane signed sin for cross-lane RY: bit==1 -> +s, bit==0 -> -s
  float ss[6];
#pragma unroll
  for (int q = 2; q < 8; ++q)
    ss[q - 2] = ((lane >> (q - 2)) & 1) ? sT[q] : -sT[q];

  // measurement weights: D[s] = sum_i alpha_i * (1 - 2*bit_i(s))
  float al[8];
#pragma unroll
  for (int q = 0; q < 8; ++q) al[q] = rfl(Wpost[q]);
  float base = 0.f;
#pragma unroll
  for (int q = 2; q < 8; ++q)
    base += ((lane >> (q - 2)) & 1) ? -al[q] : al[q];
  const float D0 = base + al[0] + al[1];
  const float D1 = base - al[0] + al[1];
  const float D2 = base + al[0] - al[1];
  const float D3 = base - al[0] - al[1];
  const float bp = rfl(bpost[0]);

  // preload first row
  const float* Ep = E + (size_t)row0 * 512;
  float4 eA = *(const float4*)(Ep + kA);
  float4 eB = *(const float4*)(Ep + kB);

  for (int r = row0; r < rowEnd; ++r) {
    // prefetch next row
    float4 nA = eA, nB = eB;
    if (r + 1 < rowEnd) {
      const float* En = E + (size_t)(r + 1) * 512;
      nA = *(const float4*)(En + kA);
      nB = *(const float4*)(En + kB);
    }

    // 10 partial reductions: sum, sumsq, 8 dots
    float f[10];
    f[0] = (eA.x + eA.y + eA.z + eA.w) + (eB.x + eB.y + eB.z + eB.w);
    f[1] = eA.x * eA.x + eA.y * eA.y + eA.z * eA.z + eA.w * eA.w
         + eB.x * eB.x + eB.y * eB.y + eB.z * eB.z + eB.w * eB.w;
#pragma unroll
    for (int j = 0; j < 8; ++j) {
      const float4 ga = gv[j][0], gb = gv[j][1];
      f[2 + j] = eA.x * ga.x + eA.y * ga.y + eA.z * ga.z + eA.w * ga.w
               + eB.x * gb.x + eB.y * gb.y + eB.z * gb.z + eB.w * gb.w;
    }
    // wave reduction: 4 DPP levels (VALU) + 2 shuffle levels (DS)
#pragma unroll
    for (int i = 0; i < 10; ++i) f[i] += dx1(f[i]);
#pragma unroll
    for (int i = 0; i < 10; ++i) f[i] += dx2(f[i]);
#pragma unroll
    for (int i = 0; i < 10; ++i) f[i] += dx4(f[i]);
#pragma unroll
    for (int i = 0; i < 10; ++i) f[i] += dx8(f[i]);
#pragma unroll
    for (int i = 0; i < 10; ++i) f[i] += sx16(f[i]);
#pragma unroll
    for (int i = 0; i < 10; ++i) f[i] += sx32(f[i]);

    const float mu = f[0] * (1.0f / 512.0f);
    const float var = f[1] * (1.0f / 512.0f) - mu * mu;
    const float rstd = rsqrtf(var + 1e-5f);

    float ca[8], sa[8];
#pragma unroll
    for (int j = 0; j < 8; ++j) {
      const float ang = rstd * (f[2 + j] - mu * G[j]) + K[j];
      const float h = 0.5f * ang;
      ca[j] = __cosf(h);
      sa[j] = __sinf(h);
    }

    // initial product state: qubit0 -> reg bit0, qubit1 -> reg bit1,
    // qubit q in 2..7 -> lane bit (q-2)
    float p = ((lane & 1)  ? sa[2] : ca[2]);
    p      *= ((lane & 2)  ? sa[3] : ca[3]);
    p      *= ((lane & 4)  ? sa[4] : ca[4]);
    p      *= ((lane & 8)  ? sa[5] : ca[5]);
    p      *= ((lane & 16) ? sa[6] : ca[6]);
    p      *= ((lane & 32) ? sa[7] : ca[7]);
    const float pc = p * ca[1], ps = p * sa[1];
    float a0 = pc * ca[0], a1 = pc * sa[0], a2 = ps * ca[0], a3 = ps * sa[0];

#define CNOT_STEP(TM, CM) { \
      const float v0 = lxor<TM>(a0); \
      const float v1 = lxor<TM>(a1); \
      const float v2 = lxor<TM>(a2); \
      const float v3 = lxor<TM>(a3); \
      const bool c = (lane & (CM)) != 0; \
      a0 = c ? v0 : a0; a1 = c ? v1 : a1; a2 = c ? v2 : a2; a3 = c ? v3 : a3; }

#define RY_STEP(M, I) { \
      const float p0 = lxor<M>(a0); \
      const float p1 = lxor<M>(a1); \
      const float p2 = lxor<M>(a2); \
      const float p3 = lxor<M>(a3); \
      a0 = cT[(I) + 2] * a0 + ss[I] * p0; \
      a1 = cT[(I) + 2] * a1 + ss[I] * p1; \
      a2 = cT[(I) + 2] * a2 + ss[I] * p2; \
      a3 = cT[(I) + 2] * a3 + ss[I] * p3; }

#pragma unroll
    for (int d = 0; d < 2; ++d) {
      // CNOT(0,1): j=1 <-> j=3 (register rename, free)
      { const float t = a1; a1 = a3; a3 = t; }
      // CNOT(1,2): reg-bit1 set -> flip lane bit0 (unconditional for a2,a3)
      a2 = dx1(a2);
      a3 = dx1(a3);
      // CNOT(q,q+1), q=2..6: control lane bit q-2, target lane bit q-1
      CNOT_STEP(2, 1)
      CNOT_STEP(4, 2)
      CNOT_STEP(8, 4)
      CNOT_STEP(16, 8)
      CNOT_STEP(32, 16)
      // CNOT(7,0): lanes with bit5 set swap (a0,a1) and (a2,a3)
      { const bool c = (lane & 32) != 0;
        const float t0 = c ? a1 : a0, t1 = c ? a0 : a1;
        const float t2 = c ? a3 : a2, t3 = c ? a2 : a3;
        a0 = t0; a1 = t1; a2 = t2; a3 = t3; }
      // RY qubit0: pairs (a0,a1),(a2,a3)
      { float t = a0; a0 = cT[0] * t - sT[0] * a1; a1 = sT[0] * t + cT[0] * a1;
        t = a2;       a2 = cT[0] * t - sT[0] * a3; a3 = sT[0] * t + cT[0] * a3; }
      // RY qubit1: pairs (a0,a2),(a1,a3)
      { float t = a0; a0 = cT[1] * t - sT[1] * a2; a2 = sT[1] * t + cT[1] * a2;
        t = a1;       a1 = cT[1] * t - sT[1] * a3; a3 = sT[1] * t + cT[1] * a3; }
      // RY qubits 2..7: butterfly on lane bit (q-2)
      RY_STEP(1, 0)
      RY_STEP(2, 1)
      RY_STEP(4, 2)
      RY_STEP(8, 3)
      RY_STEP(16, 4)
      RY_STEP(32, 5)
    }
#undef CNOT_STEP
#undef RY_STEP

    // logit = sum_s |a_s|^2 * D_s + b_post
    float v = (a0 * a0) * D0 + (a1 * a1) * D1 + (a2 * a2) * D2 + (a3 * a3) * D3;
    v = wave_allsum(v);
    if (lane == 0) out[r] = v + bp;

    eA = nA; eB = nB;
  }
}

extern "C" void kernel_launch(void* const* d_in, const int* in_sizes, int n_in,
                              void* d_out, int out_size, void* d_ws, size_t ws_size,
                              hipStream_t stream) {
  const float* E        = (const float*)d_in[0];
  const float* ln_gamma = (const float*)d_in[1];
  const float* ln_beta  = (const float*)d_in[2];
  const float* Wpre     = (const float*)d_in[3];
  const float* bpre     = (const float*)d_in[4];
  const float* theta    = (const float*)d_in[5];
  const float* Wpost    = (const float*)d_in[6];
  const float* bpost    = (const float*)d_in[7];
  float* out = (float*)d_out;

  const int nrows = in_sizes[0] / 512;
  const int rows_per_block = (BLOCK / 64) * WPW;
  const int grid = (nrows + rows_per_block - 1) / rows_per_block;
  qsco_kernel<<<grid, BLOCK, 0, stream>>>(E, ln_gamma, ln_beta, Wpre, bpre,
                                          theta, Wpost, bpost, out, nrows);
}